// Round 5
// baseline (1273.852 us; speedup 1.0000x reference)
//
#include <hip/hip_runtime.h>
#include <hip/hip_fp16.h>

// Persistent 256-block kernel (1 block/CU forced by ~156 KB LDS).
// Rows 2b,2b+1 of all 64 Omega_t cached ONCE in LDS as fp16 (validated
// R4-R8, absmax 0.0078). NTAY=3 Taylor terms of expm(A)@v.
//
// Exchange (fence-free): relaxed agent-scope 8-byte atomics only.
// TWO floats per word, tag in low-2 mantissa bits of float0. 256 words
// per round, ONE PER 64B LINE (packed layout regressed: publisher
// line-contention, R13). 4 rotating buffers (64 KB d_ws). Skew induction:
// publish rr only after full gather of rr-1 => all blocks gathered rr-2
// => distance-4 buffer + period-16 tag reuse safe. 61 rounds total.
//
// R12 FAILED (890us): device-wide atomicAdd h1 reduction serialized at MALL.
// R13 FAILED (292us): packed exchange -> publisher line serialization.
// R14 FAILED (1145us): w1h[128]+w2r[64]+w3r[16] ~= 250 regs hit the 256
//   allocator cliff -> whole array demoted to scratch (VGPR=128 reported,
//   FETCH 818 MB = per-step scratch re-reads). Structure untested.
// R15 (this round): same 4->3 RT structure, spill-proofed:
//  - 96 half2/thread W1-top (rows 0..191 per half): storage 96+64+16=176,
//    peak ~215 << 256.
//  - rows 192..255 per half read from global W1 (L2-resident, 1 MB) each
//    step: 64 coalesced dword loads/thread = 128 KB/block/step ~ 0.9us,
//    issued FIRST so they pipeline under the register-portion fma chain.
//  - init + use fully MACRO-EXPANDED (no loops) -> every w1h index is a
//    literal constant -> scratch demotion impossible.
//  - h1(s+1) computed locally by all 512 threads after T3 (~1us) instead
//    of a ~2.4us device-wide round-trip. cB[j] exchanged once at startup.
//  Kept: wave0-solo Taylor rounds, spread exchange, deferred global
//  stores (llog), ILP'd MLP, float4 omega staging.

#define NBLK 256
#define NTHR 512
#define NSTEP 20
#define NTAY 3
#define RBUF 4

typedef unsigned long long ull;

// word i (i<256) of exchange buffer buf: 64 B apart (spread layout)
#define XW(buf, i) (X + ((((buf) << 8) + (i)) << 3))

// repetition macros (compile-time-constant indices, no loops to roll)
#define REP4(M, i)  M(i) M((i)+1) M((i)+2) M((i)+3)
#define REP16(M, i) REP4(M, (i)) REP4(M, (i)+4) REP4(M, (i)+8) REP4(M, (i)+12)
#define REP48(M, i) REP16(M, (i)) REP16(M, (i)+16) REP16(M, (i)+32)
#define REP96(M, i) REP48(M, (i)) REP48(M, (i)+48)

__device__ __forceinline__ void wredsum2(float& p0, float& p1) {
#pragma unroll
  for (int off = 32; off > 0; off >>= 1) {
    float t0 = __shfl_xor(p0, off, 64);
    float t1 = __shfl_xor(p1, off, 64);
    p0 += t0;
    p1 += t1;
  }
}

__device__ __forceinline__ void publish2(ull* w, float v0, float v1, unsigned int tag2) {
  unsigned int u0 = (__float_as_uint(v0) & ~3u) | tag2;
  ull x = (ull)u0 | ((ull)__float_as_uint(v1) << 32);
  __hip_atomic_store(w, x, __ATOMIC_RELAXED, __HIP_MEMORY_SCOPE_AGENT);
}

__device__ __forceinline__ float2 poll2(ull* w, unsigned int tag2) {
  int it = 0;
  for (;;) {
    ull x = __hip_atomic_load(w, __ATOMIC_RELAXED, __HIP_MEMORY_SCOPE_AGENT);
    if ((unsigned int)(x & 3u) == tag2) {
      float2 r;
      r.x = __uint_as_float((unsigned int)x);
      r.y = __uint_as_float((unsigned int)(x >> 32));
      return r;
    }
    if (it == 0)      __builtin_amdgcn_s_sleep(1);
    else if (it == 1) __builtin_amdgcn_s_sleep(2);
    else              __builtin_amdgcn_s_sleep(4);
    if (it < 2) ++it;
  }
}

// lane-quad poll: 4 words (64 B apart) -> 8 floats; all 4 loads kept in
// flight per retry iteration (hand-unrolled, no runtime-indexed arrays).
__device__ __forceinline__ void poll8(ull* w0, unsigned int tg, float* o) {
  ull x0 = 0, x1 = 0, x2 = 0, x3 = 0;
  bool g0 = false, g1 = false, g2 = false, g3 = false;
  int it = 0;
  for (;;) {
    if (!g0) { ull x = __hip_atomic_load(w0,      __ATOMIC_RELAXED, __HIP_MEMORY_SCOPE_AGENT); if ((unsigned int)(x & 3u) == tg) { x0 = x; g0 = true; } }
    if (!g1) { ull x = __hip_atomic_load(w0 + 8,  __ATOMIC_RELAXED, __HIP_MEMORY_SCOPE_AGENT); if ((unsigned int)(x & 3u) == tg) { x1 = x; g1 = true; } }
    if (!g2) { ull x = __hip_atomic_load(w0 + 16, __ATOMIC_RELAXED, __HIP_MEMORY_SCOPE_AGENT); if ((unsigned int)(x & 3u) == tg) { x2 = x; g2 = true; } }
    if (!g3) { ull x = __hip_atomic_load(w0 + 24, __ATOMIC_RELAXED, __HIP_MEMORY_SCOPE_AGENT); if ((unsigned int)(x & 3u) == tg) { x3 = x; g3 = true; } }
    if (g0 && g1 && g2 && g3) break;
    if (it == 0)      __builtin_amdgcn_s_sleep(1);
    else if (it == 1) __builtin_amdgcn_s_sleep(2);
    else              __builtin_amdgcn_s_sleep(4);
    if (it < 2) ++it;
  }
  o[0] = __uint_as_float((unsigned int)x0); o[1] = __uint_as_float((unsigned int)(x0 >> 32));
  o[2] = __uint_as_float((unsigned int)x1); o[3] = __uint_as_float((unsigned int)(x1 >> 32));
  o[4] = __uint_as_float((unsigned int)x2); o[5] = __uint_as_float((unsigned int)(x2 >> 32));
  o[6] = __uint_as_float((unsigned int)x3); o[7] = __uint_as_float((unsigned int)(x3 >> 32));
}

__global__ __launch_bounds__(NTHR, 2) void petri_kernel(
    const float* __restrict__ vsrc, const float* __restrict__ vtgt,
    const float* __restrict__ omg,  const float* __restrict__ W1,
    const float* __restrict__ b1,   const float* __restrict__ W2,
    const float* __restrict__ b2,   const float* __restrict__ W3,
    const float* __restrict__ b3,   const float* __restrict__ gum,
    ull* __restrict__ X, float* __restrict__ out) {
  __shared__ __half2 oh[64 * 512];   // 128 KB: {row2b[j], row2b+1[j]} per t
  __shared__ __align__(16) float A0_s[512];
  __shared__ __align__(16) float A1_s[512];
  __shared__ __align__(16) float v_loc[512];
  __shared__ float tgt_s[512];
  __shared__ float w1c_s[1024];      // W1 column b (both halves; startup only)
  __shared__ float cB_s[256];        // cB[j] (gathered at startup)
  __shared__ float gum_s[NSTEP * 64];
  __shared__ float b2_s[128], b3_s[64];
  __shared__ float soft_s[64], h1_s[256], h2_s[128];
  __shared__ float redp[512];
  __shared__ float llog[NSTEP * 64]; // deferred logits
  __shared__ float rf8[8], rf8b[8];
  __shared__ int   ri8[8];
  __shared__ int   bc[1];

  const int b = blockIdx.x, tid = threadIdx.x;
  const int wv = tid >> 6, ln = tid & 63;
  const int jj = tid & 255, hh = tid >> 8;  // h1-compute mapping

  v_loc[tid] = vsrc[tid];
  tgt_s[tid] = vtgt[tid];
  w1c_s[tid] = W1[tid * 256 + b];
  w1c_s[tid + 512] = W1[(tid + 512) * 256 + b];
  for (int i = tid; i < NSTEP * 64; i += NTHR) gum_s[i] = gum[i];
  if (tid >= NTHR - 128) {
    int j = tid - (NTHR - 128);
    b2_s[j] = b2[j];
    if (j < 64) b3_s[j] = b3[j];
  }
  // W2 column slice in registers: thread (o=tid&127,q=tid>>7) holds
  // W2[(q*64+i)*128+o], i=0..63
  float w2r[64];
  {
    const int o = tid & 127, q = tid >> 7;
    const float* p = W2 + ((q << 6) * 128) + o;
#pragma unroll
    for (int i = 0; i < 64; ++i) w2r[i] = p[i * 128];
  }
  // W3 slice: thread (o=tid&63,q=tid>>6) holds W3[(q*16+i)*64+o], i=0..15
  float w3r[16];
  {
    const int o = tid & 63, q = tid >> 6;
    const float* p = W3 + ((q << 4) * 64) + o;
#pragma unroll
    for (int i = 0; i < 16; ++i) w3r[i] = p[i * 64];
  }
  // R15: W1-top partial slice in fp16 registers, MACRO-EXPANDED (no loops
  // -> all indices literal -> cannot be demoted to scratch).
  // Thread (jj, hh) holds W1[hh*256 + {2i,2i+1}, jj] in w1h[i], i=0..95
  // (v-elems 0..191 of its half). Rows 192..255 read from global per step.
  __half2 w1h[96];
  {
    const float* wp = W1 + ((hh << 8) * 256) + jj;
#define W1LD(i) w1h[i] = __floats2half2_rn(wp[(2*(i))*256], wp[(2*(i)+1)*256]);
    REP96(W1LD, 0)
#undef W1LD
  }
  // Omega rows 2b,2b+1 -> LDS fp16, float4-vectorized
  {
    const int tq = tid >> 7;            // 0..3 : t within group of 4
    const int c4 = (tid & 127) << 2;    // col 0..508 step 4
    const float* rp = omg + (b << 10) + c4;
#pragma unroll 4
    for (int g = 0; g < 16; ++g) {
      const int t = (g << 2) + tq;
      const float* p = rp + t * 262144;
      const float4 f0 = *(const float4*)(p);        // row 2b
      const float4 f1 = *(const float4*)(p + 512);  // row 2b+1
      __half2* dst = oh + t * 512 + c4;
      dst[0] = __floats2half2_rn(f0.x, f1.x);
      dst[1] = __floats2half2_rn(f0.y, f1.y);
      dst[2] = __floats2half2_rn(f0.z, f1.z);
      dst[3] = __floats2half2_rn(f0.w, f1.w);
    }
  }
  __syncthreads();

  // startup round 0: publish {h1_step0[b], cB[b]}; gather both vectors.
  {
    float p0 = tgt_s[tid] * w1c_s[tid + 512];   // -> cB
    float p1 = v_loc[tid] * w1c_s[tid];         // -> h1 of step 0
    wredsum2(p0, p1);
    if (ln == 0) { rf8[wv] = p0; rf8b[wv] = p1; }
    __syncthreads();
    if (tid == 0) {
      float cB = b1[b], dv = 0.f;
      for (int q = 0; q < 8; ++q) { cB += rf8[q]; dv += rf8b[q]; }
      publish2(XW(0, b), fmaxf(dv + cB, 0.f), cB, 0u);
    }
    if (tid < 256) {
      float2 g = poll2(XW(0, tid), 0u);
      h1_s[tid] = g.x;
      cB_s[tid] = g.y;
    }
    __syncthreads();
  }

  // target argmax (identical in every block), first-index tie-break
  int tgtIdx;
  {
    float v = tgt_s[tid]; int ix = tid;
#pragma unroll
    for (int off = 32; off > 0; off >>= 1) {
      float ov = __shfl_xor(v, off, 64); int oi = __shfl_xor(ix, off, 64);
      if (ov > v || (ov == v && oi < ix)) { v = ov; ix = oi; }
    }
    if (ln == 0) { rf8[wv] = v; ri8[wv] = ix; }
    __syncthreads();
    if (tid == 0) {
      float bv = rf8[0]; int bix = ri8[0];
      for (int q = 1; q < 8; ++q)
        if (rf8[q] > bv || (rf8[q] == bv && ri8[q] < bix)) { bv = rf8[q]; bix = ri8[q]; }
      bc[0] = bix;
    }
    __syncthreads();
    tgtIdx = bc[0];
    __syncthreads();
  }

  int d = 0;
  int nAct = 0;  // number of active steps (uniform across blocks/threads)
  int r = 1;     // round counter; round 0 was startup. Step s: T1..T3.

  for (int s = 0; s < NSTEP; ++s) {
    if (d) continue;  // frozen (uniform across blocks); epilogue zero-fills
    nAct = s + 1;

    // ---- replicated L2/L3/softmax from h1_s (register weights) ----
    {
      const int q = tid >> 7;
      const float* hp = h1_s + (q << 6);
      float a0 = 0.f, a1 = 0.f, a2 = 0.f, a3 = 0.f;
#pragma unroll
      for (int i = 0; i < 64; i += 4) {
        a0 = fmaf(hp[i],     w2r[i],     a0);
        a1 = fmaf(hp[i + 1], w2r[i + 1], a1);
        a2 = fmaf(hp[i + 2], w2r[i + 2], a2);
        a3 = fmaf(hp[i + 3], w2r[i + 3], a3);
      }
      redp[tid] = (a0 + a1) + (a2 + a3);
    }
    __syncthreads();
    if (tid < 128) {
      float rr = redp[tid] + redp[tid + 128] + redp[tid + 256] + redp[tid + 384] + b2_s[tid];
      h2_s[tid] = fmaxf(rr, 0.f);
    }
    __syncthreads();
    {
      const int q = tid >> 6;
      const float* hp = h2_s + (q << 4);
      float a0 = 0.f, a1 = 0.f;
#pragma unroll
      for (int i = 0; i < 16; i += 2) {
        a0 = fmaf(hp[i],     w3r[i],     a0);
        a1 = fmaf(hp[i + 1], w3r[i + 1], a1);
      }
      redp[tid] = a0 + a1;
    }
    __syncthreads();
    if (tid < 64) {
      float a = b3_s[tid];
#pragma unroll
      for (int q = 0; q < 8; ++q) a += redp[tid + (q << 6)];
      float lg = a + gum_s[s * 64 + tid];  // TAU = 1
      float mx = lg;
#pragma unroll
      for (int off = 32; off > 0; off >>= 1) mx = fmaxf(mx, __shfl_xor(mx, off, 64));
      float e = __expf(lg - mx);
      float sm = e;
#pragma unroll
      for (int off = 32; off > 0; off >>= 1) sm += __shfl_xor(sm, off, 64);
      soft_s[tid] = e / sm;
      llog[s * 64 + tid] = a;  // deferred logits
    }
    __syncthreads();

    // ---- mix 2 rows of A from LDS fp16 ----
    {
      float a0 = 0.f, a1 = 0.f, c0 = 0.f, c1 = 0.f;
#pragma unroll 8
      for (int t = 0; t < 64; t += 2) {
        float2 xy0 = __half22float2(oh[t * 512 + tid]);
        float2 xy1 = __half22float2(oh[(t + 1) * 512 + tid]);
        float s0 = soft_s[t], s1 = soft_s[t + 1];
        a0 = fmaf(s0, xy0.x, a0);
        c0 = fmaf(s0, xy0.y, c0);
        a1 = fmaf(s1, xy1.x, a1);
        c1 = fmaf(s1, xy1.y, c1);
      }
      A0_s[tid] = a0 + a1;
      A1_s[tid] = c0 + c1;
    }
    __syncthreads();

    // ---- rounds r..r+2: Taylor n=1..NTAY, wave0 solo, barrier-free ----
    if (wv == 0) {
      const int l8 = ln << 3;
      const float4 a00 = *(const float4*)(A0_s + l8);      // A row 2b
      const float4 a01 = *(const float4*)(A0_s + l8 + 4);
      const float4 a10 = *(const float4*)(A1_s + l8);      // A row 2b+1
      const float4 a11 = *(const float4*)(A1_s + l8 + 4);
      const float vb0 = v_loc[b << 1], vb1 = v_loc[(b << 1) + 1];
      float wreg[8];
      {
        const float4 v0 = *(const float4*)(v_loc + l8);
        const float4 v1 = *(const float4*)(v_loc + l8 + 4);
        wreg[0] = v0.x; wreg[1] = v0.y; wreg[2] = v0.z; wreg[3] = v0.w;
        wreg[4] = v1.x; wreg[5] = v1.y; wreg[6] = v1.z; wreg[7] = v1.w;
      }
      float acc0 = 0.f, acc1 = 0.f;
#pragma unroll
      for (int n = 1; n <= NTAY; ++n) {
        const int rr = r + (n - 1);
        const int buf = rr & (RBUF - 1);
        const unsigned int tg = (unsigned int)((rr >> 2) & 3);
        float p0 = 0.f, p1 = 0.f;
        p0 = fmaf(a00.x, wreg[0], p0); p0 = fmaf(a00.y, wreg[1], p0);
        p0 = fmaf(a00.z, wreg[2], p0); p0 = fmaf(a00.w, wreg[3], p0);
        p0 = fmaf(a01.x, wreg[4], p0); p0 = fmaf(a01.y, wreg[5], p0);
        p0 = fmaf(a01.z, wreg[6], p0); p0 = fmaf(a01.w, wreg[7], p0);
        p1 = fmaf(a10.x, wreg[0], p1); p1 = fmaf(a10.y, wreg[1], p1);
        p1 = fmaf(a10.z, wreg[2], p1); p1 = fmaf(a10.w, wreg[3], p1);
        p1 = fmaf(a11.x, wreg[4], p1); p1 = fmaf(a11.y, wreg[5], p1);
        p1 = fmaf(a11.z, wreg[6], p1); p1 = fmaf(a11.w, wreg[7], p1);
        wredsum2(p0, p1);
        if (ln == 0) {
          float s0, s1;
          if (n == 1) {
            s0 = p0; s1 = p1;
            acc0 = vb0 + s0; acc1 = vb1 + s1;
          } else {
            const float inv = (n == 2) ? 0.5f : (1.0f / 3.0f);
            s0 = p0 * inv; s1 = p1 * inv;
            acc0 += s0; acc1 += s1;
          }
          const float q0 = (n < NTAY) ? s0 : acc0;  // last round: vnew
          const float q1 = (n < NTAY) ? s1 : acc1;
          publish2(XW(buf, b), q0, q1, tg);
        }
        poll8(XW(buf, (ln << 2)), tg, wreg);
      }
      // vnew -> LDS; solo argmax; done flag
      *(float4*)(v_loc + l8)     = make_float4(wreg[0], wreg[1], wreg[2], wreg[3]);
      *(float4*)(v_loc + l8 + 4) = make_float4(wreg[4], wreg[5], wreg[6], wreg[7]);
      float mv = wreg[0]; int mi = l8;
#pragma unroll
      for (int k = 1; k < 8; ++k) if (wreg[k] > mv) { mv = wreg[k]; mi = l8 + k; }
#pragma unroll
      for (int off = 32; off > 0; off >>= 1) {
        float ov = __shfl_xor(mv, off, 64); int oi = __shfl_xor(mi, off, 64);
        if (ov > mv || (ov == mv && oi < mi)) { mv = ov; mi = oi; }
      }
      if (ln == 0) bc[0] = (mi == tgtIdx) ? 1 : 0;
    }
    __syncthreads();
    if (bc[0]) {
      d = 1;
    } else if (s + 1 < NSTEP) {
      // ---- R15: local h1 for step s+1 (no exchange round). ----
      // Thread (jj, hh): partial dot over v[hh*256 .. +255].
      // Global tail (rows 192..255) issued FIRST -> loads pipeline under
      // the register-portion fma chain. All LDS v-reads are wave-uniform
      // (broadcast, conflict-free).
      const float4* vp4 = (const float4*)(v_loc + (hh << 8));
      const float* wgp = W1 + (((hh << 8) + 192) * 256) + jj;
      float acA = 0.f, acB = 0.f, acC = 0.f, acD = 0.f;
#define H1G4(k) { const float4 v4_ = vp4[48 + (k)]; \
      acA = fmaf(wgp[(4*(k))*256],     v4_.x, acA); \
      acB = fmaf(wgp[(4*(k)+1)*256],   v4_.y, acB); \
      acC = fmaf(wgp[(4*(k)+2)*256],   v4_.z, acC); \
      acD = fmaf(wgp[(4*(k)+3)*256],   v4_.w, acD); }
      REP16(H1G4, 0)
#undef H1G4
#define H1FMA(i) { const float4 v4_ = vp4[i]; \
      const float2 wa_ = __half22float2(w1h[2*(i)]); \
      const float2 wb_ = __half22float2(w1h[2*(i)+1]); \
      acA = fmaf(wa_.x, v4_.x, acA); acB = fmaf(wa_.y, v4_.y, acB); \
      acC = fmaf(wb_.x, v4_.z, acC); acD = fmaf(wb_.y, v4_.w, acD); }
      REP48(H1FMA, 0)
#undef H1FMA
      redp[tid] = (acA + acB) + (acC + acD);
      __syncthreads();
      if (tid < 256)
        h1_s[tid] = fmaxf(redp[tid] + redp[tid + 256] + cB_s[tid], 0.f);
      __syncthreads();
    }
    r += NTAY;
  }

  // ---- epilogue: all global writes (block 0 only) ----
  if (b == 0) {
    out[tid] = v_loc[tid];
    for (int i = tid; i < NSTEP * 64; i += NTHR)
      out[512 + i] = (i < nAct * 64) ? llog[i] : 0.0f;
  }
}

extern "C" void kernel_launch(void* const* d_in, const int* in_sizes, int n_in,
                              void* d_out, int out_size, void* d_ws, size_t ws_size,
                              hipStream_t stream) {
  (void)in_sizes; (void)n_in; (void)out_size; (void)ws_size;
  petri_kernel<<<dim3(NBLK), dim3(NTHR), 0, stream>>>(
      (const float*)d_in[0], (const float*)d_in[1], (const float*)d_in[2],
      (const float*)d_in[3], (const float*)d_in[4], (const float*)d_in[5],
      (const float*)d_in[6], (const float*)d_in[7], (const float*)d_in[8],
      (const float*)d_in[9], (ull*)d_ws, (float*)d_out);
}

// Round 6
// 1272.753 us; speedup vs baseline: 1.0009x; 1.0009x over previous
//
#include <hip/hip_runtime.h>
#include <hip/hip_fp16.h>

// Persistent 256-block kernel (1 block/CU forced by ~156 KB LDS).
// Rows 2b,2b+1 of all 64 Omega_t cached ONCE in LDS as fp16 (validated
// R4-R8, absmax 0.0078). NTAY=3 Taylor terms of expm(A)@v.
//
// Exchange (fence-free): relaxed agent-scope 8-byte atomics only.
// TWO floats per word, tag in low-2 mantissa bits of float0. 256 words
// per round, ONE PER 64B LINE (packed layout regressed: publisher
// line-contention, R13). 4 rotating buffers (64 KB d_ws). Skew induction:
// publish rr only after full gather of rr-1 => all blocks gathered rr-2
// => distance-4 buffer + period-16 tag reuse safe. 61 rounds total.
//
// R12 FAILED (890us): device-wide atomicAdd h1 reduction serialized at MALL.
// R13 FAILED (292us): packed exchange -> publisher line serialization.
// R14 FAILED (1145us): w1h spilled to scratch (VGPR=128, FETCH 818MB).
// R15 FAILED (1187us): spilled AGAIN despite macro-expanded literal
//   indices. Diagnosis: the allocator TARGETS 4 waves/EU (=128 VGPR)
//   because __launch_bounds__'s 2nd arg is only a MINIMUM; it ignores
//   that LDS already caps us at 2 waves/EU, and spills to hit 128.
// R16 (this round): R15 VERBATIM + __attribute__((amdgpu_waves_per_eu(2,2)))
//   -> allocator's max-occupancy target = the LDS-forced reality ->
//   256-VGPR budget -> w1h (96) + w2r (64) + w3r (16) + working ~220 fits.
//   Single-variable change; decisive signal is VGPR_Count ~230-256 and
//   FETCH back to ~45 MB.
//  Structure (from R15): 3 round-trips/step (T1,T2,T3). h1(s+1) computed
//  LOCALLY by all 512 threads after T3 (wave0's poll8 gives full vnew;
//  W1-top rows 0..191/half in fp16 regs, rows 192..255/half from
//  L2-resident global W1). cB exchanged once at startup.

#define NBLK 256
#define NTHR 512
#define NSTEP 20
#define NTAY 3
#define RBUF 4

typedef unsigned long long ull;

// word i (i<256) of exchange buffer buf: 64 B apart (spread layout)
#define XW(buf, i) (X + ((((buf) << 8) + (i)) << 3))

// repetition macros (compile-time-constant indices, no loops to roll)
#define REP4(M, i)  M(i) M((i)+1) M((i)+2) M((i)+3)
#define REP16(M, i) REP4(M, (i)) REP4(M, (i)+4) REP4(M, (i)+8) REP4(M, (i)+12)
#define REP48(M, i) REP16(M, (i)) REP16(M, (i)+16) REP16(M, (i)+32)
#define REP96(M, i) REP48(M, (i)) REP48(M, (i)+48)

__device__ __forceinline__ void wredsum2(float& p0, float& p1) {
#pragma unroll
  for (int off = 32; off > 0; off >>= 1) {
    float t0 = __shfl_xor(p0, off, 64);
    float t1 = __shfl_xor(p1, off, 64);
    p0 += t0;
    p1 += t1;
  }
}

__device__ __forceinline__ void publish2(ull* w, float v0, float v1, unsigned int tag2) {
  unsigned int u0 = (__float_as_uint(v0) & ~3u) | tag2;
  ull x = (ull)u0 | ((ull)__float_as_uint(v1) << 32);
  __hip_atomic_store(w, x, __ATOMIC_RELAXED, __HIP_MEMORY_SCOPE_AGENT);
}

__device__ __forceinline__ float2 poll2(ull* w, unsigned int tag2) {
  int it = 0;
  for (;;) {
    ull x = __hip_atomic_load(w, __ATOMIC_RELAXED, __HIP_MEMORY_SCOPE_AGENT);
    if ((unsigned int)(x & 3u) == tag2) {
      float2 r;
      r.x = __uint_as_float((unsigned int)x);
      r.y = __uint_as_float((unsigned int)(x >> 32));
      return r;
    }
    if (it == 0)      __builtin_amdgcn_s_sleep(1);
    else if (it == 1) __builtin_amdgcn_s_sleep(2);
    else              __builtin_amdgcn_s_sleep(4);
    if (it < 2) ++it;
  }
}

// lane-quad poll: 4 words (64 B apart) -> 8 floats; all 4 loads kept in
// flight per retry iteration (hand-unrolled, no runtime-indexed arrays).
__device__ __forceinline__ void poll8(ull* w0, unsigned int tg, float* o) {
  ull x0 = 0, x1 = 0, x2 = 0, x3 = 0;
  bool g0 = false, g1 = false, g2 = false, g3 = false;
  int it = 0;
  for (;;) {
    if (!g0) { ull x = __hip_atomic_load(w0,      __ATOMIC_RELAXED, __HIP_MEMORY_SCOPE_AGENT); if ((unsigned int)(x & 3u) == tg) { x0 = x; g0 = true; } }
    if (!g1) { ull x = __hip_atomic_load(w0 + 8,  __ATOMIC_RELAXED, __HIP_MEMORY_SCOPE_AGENT); if ((unsigned int)(x & 3u) == tg) { x1 = x; g1 = true; } }
    if (!g2) { ull x = __hip_atomic_load(w0 + 16, __ATOMIC_RELAXED, __HIP_MEMORY_SCOPE_AGENT); if ((unsigned int)(x & 3u) == tg) { x2 = x; g2 = true; } }
    if (!g3) { ull x = __hip_atomic_load(w0 + 24, __ATOMIC_RELAXED, __HIP_MEMORY_SCOPE_AGENT); if ((unsigned int)(x & 3u) == tg) { x3 = x; g3 = true; } }
    if (g0 && g1 && g2 && g3) break;
    if (it == 0)      __builtin_amdgcn_s_sleep(1);
    else if (it == 1) __builtin_amdgcn_s_sleep(2);
    else              __builtin_amdgcn_s_sleep(4);
    if (it < 2) ++it;
  }
  o[0] = __uint_as_float((unsigned int)x0); o[1] = __uint_as_float((unsigned int)(x0 >> 32));
  o[2] = __uint_as_float((unsigned int)x1); o[3] = __uint_as_float((unsigned int)(x1 >> 32));
  o[4] = __uint_as_float((unsigned int)x2); o[5] = __uint_as_float((unsigned int)(x2 >> 32));
  o[6] = __uint_as_float((unsigned int)x3); o[7] = __uint_as_float((unsigned int)(x3 >> 32));
}

__global__ __attribute__((amdgpu_waves_per_eu(2, 2)))
__launch_bounds__(NTHR) void petri_kernel(
    const float* __restrict__ vsrc, const float* __restrict__ vtgt,
    const float* __restrict__ omg,  const float* __restrict__ W1,
    const float* __restrict__ b1,   const float* __restrict__ W2,
    const float* __restrict__ b2,   const float* __restrict__ W3,
    const float* __restrict__ b3,   const float* __restrict__ gum,
    ull* __restrict__ X, float* __restrict__ out) {
  __shared__ __half2 oh[64 * 512];   // 128 KB: {row2b[j], row2b+1[j]} per t
  __shared__ __align__(16) float A0_s[512];
  __shared__ __align__(16) float A1_s[512];
  __shared__ __align__(16) float v_loc[512];
  __shared__ float tgt_s[512];
  __shared__ float w1c_s[1024];      // W1 column b (both halves; startup only)
  __shared__ float cB_s[256];        // cB[j] (gathered at startup)
  __shared__ float gum_s[NSTEP * 64];
  __shared__ float b2_s[128], b3_s[64];
  __shared__ float soft_s[64], h1_s[256], h2_s[128];
  __shared__ float redp[512];
  __shared__ float llog[NSTEP * 64]; // deferred logits
  __shared__ float rf8[8], rf8b[8];
  __shared__ int   ri8[8];
  __shared__ int   bc[1];

  const int b = blockIdx.x, tid = threadIdx.x;
  const int wv = tid >> 6, ln = tid & 63;
  const int jj = tid & 255, hh = tid >> 8;  // h1-compute mapping

  v_loc[tid] = vsrc[tid];
  tgt_s[tid] = vtgt[tid];
  w1c_s[tid] = W1[tid * 256 + b];
  w1c_s[tid + 512] = W1[(tid + 512) * 256 + b];
  for (int i = tid; i < NSTEP * 64; i += NTHR) gum_s[i] = gum[i];
  if (tid >= NTHR - 128) {
    int j = tid - (NTHR - 128);
    b2_s[j] = b2[j];
    if (j < 64) b3_s[j] = b3[j];
  }
  // W2 column slice in registers: thread (o=tid&127,q=tid>>7) holds
  // W2[(q*64+i)*128+o], i=0..63
  float w2r[64];
  {
    const int o = tid & 127, q = tid >> 7;
    const float* p = W2 + ((q << 6) * 128) + o;
#pragma unroll
    for (int i = 0; i < 64; ++i) w2r[i] = p[i * 128];
  }
  // W3 slice: thread (o=tid&63,q=tid>>6) holds W3[(q*16+i)*64+o], i=0..15
  float w3r[16];
  {
    const int o = tid & 63, q = tid >> 6;
    const float* p = W3 + ((q << 4) * 64) + o;
#pragma unroll
    for (int i = 0; i < 16; ++i) w3r[i] = p[i * 64];
  }
  // W1-top partial slice in fp16 registers, macro-expanded (literal idx).
  // Thread (jj, hh) holds W1[hh*256 + {2i,2i+1}, jj] in w1h[i], i=0..95
  // (v-elems 0..191 of its half). Rows 192..255 read from global per step.
  __half2 w1h[96];
  {
    const float* wp = W1 + ((hh << 8) * 256) + jj;
#define W1LD(i) w1h[i] = __floats2half2_rn(wp[(2*(i))*256], wp[(2*(i)+1)*256]);
    REP96(W1LD, 0)
#undef W1LD
  }
  // Omega rows 2b,2b+1 -> LDS fp16, float4-vectorized
  {
    const int tq = tid >> 7;            // 0..3 : t within group of 4
    const int c4 = (tid & 127) << 2;    // col 0..508 step 4
    const float* rp = omg + (b << 10) + c4;
#pragma unroll 4
    for (int g = 0; g < 16; ++g) {
      const int t = (g << 2) + tq;
      const float* p = rp + t * 262144;
      const float4 f0 = *(const float4*)(p);        // row 2b
      const float4 f1 = *(const float4*)(p + 512);  // row 2b+1
      __half2* dst = oh + t * 512 + c4;
      dst[0] = __floats2half2_rn(f0.x, f1.x);
      dst[1] = __floats2half2_rn(f0.y, f1.y);
      dst[2] = __floats2half2_rn(f0.z, f1.z);
      dst[3] = __floats2half2_rn(f0.w, f1.w);
    }
  }
  __syncthreads();

  // startup round 0: publish {h1_step0[b], cB[b]}; gather both vectors.
  {
    float p0 = tgt_s[tid] * w1c_s[tid + 512];   // -> cB
    float p1 = v_loc[tid] * w1c_s[tid];         // -> h1 of step 0
    wredsum2(p0, p1);
    if (ln == 0) { rf8[wv] = p0; rf8b[wv] = p1; }
    __syncthreads();
    if (tid == 0) {
      float cB = b1[b], dv = 0.f;
      for (int q = 0; q < 8; ++q) { cB += rf8[q]; dv += rf8b[q]; }
      publish2(XW(0, b), fmaxf(dv + cB, 0.f), cB, 0u);
    }
    if (tid < 256) {
      float2 g = poll2(XW(0, tid), 0u);
      h1_s[tid] = g.x;
      cB_s[tid] = g.y;
    }
    __syncthreads();
  }

  // target argmax (identical in every block), first-index tie-break
  int tgtIdx;
  {
    float v = tgt_s[tid]; int ix = tid;
#pragma unroll
    for (int off = 32; off > 0; off >>= 1) {
      float ov = __shfl_xor(v, off, 64); int oi = __shfl_xor(ix, off, 64);
      if (ov > v || (ov == v && oi < ix)) { v = ov; ix = oi; }
    }
    if (ln == 0) { rf8[wv] = v; ri8[wv] = ix; }
    __syncthreads();
    if (tid == 0) {
      float bv = rf8[0]; int bix = ri8[0];
      for (int q = 1; q < 8; ++q)
        if (rf8[q] > bv || (rf8[q] == bv && ri8[q] < bix)) { bv = rf8[q]; bix = ri8[q]; }
      bc[0] = bix;
    }
    __syncthreads();
    tgtIdx = bc[0];
    __syncthreads();
  }

  int d = 0;
  int nAct = 0;  // number of active steps (uniform across blocks/threads)
  int r = 1;     // round counter; round 0 was startup. Step s: T1..T3.

  for (int s = 0; s < NSTEP; ++s) {
    if (d) continue;  // frozen (uniform across blocks); epilogue zero-fills
    nAct = s + 1;

    // ---- replicated L2/L3/softmax from h1_s (register weights) ----
    {
      const int q = tid >> 7;
      const float* hp = h1_s + (q << 6);
      float a0 = 0.f, a1 = 0.f, a2 = 0.f, a3 = 0.f;
#pragma unroll
      for (int i = 0; i < 64; i += 4) {
        a0 = fmaf(hp[i],     w2r[i],     a0);
        a1 = fmaf(hp[i + 1], w2r[i + 1], a1);
        a2 = fmaf(hp[i + 2], w2r[i + 2], a2);
        a3 = fmaf(hp[i + 3], w2r[i + 3], a3);
      }
      redp[tid] = (a0 + a1) + (a2 + a3);
    }
    __syncthreads();
    if (tid < 128) {
      float rr = redp[tid] + redp[tid + 128] + redp[tid + 256] + redp[tid + 384] + b2_s[tid];
      h2_s[tid] = fmaxf(rr, 0.f);
    }
    __syncthreads();
    {
      const int q = tid >> 6;
      const float* hp = h2_s + (q << 4);
      float a0 = 0.f, a1 = 0.f;
#pragma unroll
      for (int i = 0; i < 16; i += 2) {
        a0 = fmaf(hp[i],     w3r[i],     a0);
        a1 = fmaf(hp[i + 1], w3r[i + 1], a1);
      }
      redp[tid] = a0 + a1;
    }
    __syncthreads();
    if (tid < 64) {
      float a = b3_s[tid];
#pragma unroll
      for (int q = 0; q < 8; ++q) a += redp[tid + (q << 6)];
      float lg = a + gum_s[s * 64 + tid];  // TAU = 1
      float mx = lg;
#pragma unroll
      for (int off = 32; off > 0; off >>= 1) mx = fmaxf(mx, __shfl_xor(mx, off, 64));
      float e = __expf(lg - mx);
      float sm = e;
#pragma unroll
      for (int off = 32; off > 0; off >>= 1) sm += __shfl_xor(sm, off, 64);
      soft_s[tid] = e / sm;
      llog[s * 64 + tid] = a;  // deferred logits
    }
    __syncthreads();

    // ---- mix 2 rows of A from LDS fp16 ----
    {
      float a0 = 0.f, a1 = 0.f, c0 = 0.f, c1 = 0.f;
#pragma unroll 8
      for (int t = 0; t < 64; t += 2) {
        float2 xy0 = __half22float2(oh[t * 512 + tid]);
        float2 xy1 = __half22float2(oh[(t + 1) * 512 + tid]);
        float s0 = soft_s[t], s1 = soft_s[t + 1];
        a0 = fmaf(s0, xy0.x, a0);
        c0 = fmaf(s0, xy0.y, c0);
        a1 = fmaf(s1, xy1.x, a1);
        c1 = fmaf(s1, xy1.y, c1);
      }
      A0_s[tid] = a0 + a1;
      A1_s[tid] = c0 + c1;
    }
    __syncthreads();

    // ---- rounds r..r+2: Taylor n=1..NTAY, wave0 solo, barrier-free ----
    if (wv == 0) {
      const int l8 = ln << 3;
      const float4 a00 = *(const float4*)(A0_s + l8);      // A row 2b
      const float4 a01 = *(const float4*)(A0_s + l8 + 4);
      const float4 a10 = *(const float4*)(A1_s + l8);      // A row 2b+1
      const float4 a11 = *(const float4*)(A1_s + l8 + 4);
      const float vb0 = v_loc[b << 1], vb1 = v_loc[(b << 1) + 1];
      float wreg[8];
      {
        const float4 v0 = *(const float4*)(v_loc + l8);
        const float4 v1 = *(const float4*)(v_loc + l8 + 4);
        wreg[0] = v0.x; wreg[1] = v0.y; wreg[2] = v0.z; wreg[3] = v0.w;
        wreg[4] = v1.x; wreg[5] = v1.y; wreg[6] = v1.z; wreg[7] = v1.w;
      }
      float acc0 = 0.f, acc1 = 0.f;
#pragma unroll
      for (int n = 1; n <= NTAY; ++n) {
        const int rr = r + (n - 1);
        const int buf = rr & (RBUF - 1);
        const unsigned int tg = (unsigned int)((rr >> 2) & 3);
        float p0 = 0.f, p1 = 0.f;
        p0 = fmaf(a00.x, wreg[0], p0); p0 = fmaf(a00.y, wreg[1], p0);
        p0 = fmaf(a00.z, wreg[2], p0); p0 = fmaf(a00.w, wreg[3], p0);
        p0 = fmaf(a01.x, wreg[4], p0); p0 = fmaf(a01.y, wreg[5], p0);
        p0 = fmaf(a01.z, wreg[6], p0); p0 = fmaf(a01.w, wreg[7], p0);
        p1 = fmaf(a10.x, wreg[0], p1); p1 = fmaf(a10.y, wreg[1], p1);
        p1 = fmaf(a10.z, wreg[2], p1); p1 = fmaf(a10.w, wreg[3], p1);
        p1 = fmaf(a11.x, wreg[4], p1); p1 = fmaf(a11.y, wreg[5], p1);
        p1 = fmaf(a11.z, wreg[6], p1); p1 = fmaf(a11.w, wreg[7], p1);
        wredsum2(p0, p1);
        if (ln == 0) {
          float s0, s1;
          if (n == 1) {
            s0 = p0; s1 = p1;
            acc0 = vb0 + s0; acc1 = vb1 + s1;
          } else {
            const float inv = (n == 2) ? 0.5f : (1.0f / 3.0f);
            s0 = p0 * inv; s1 = p1 * inv;
            acc0 += s0; acc1 += s1;
          }
          const float q0 = (n < NTAY) ? s0 : acc0;  // last round: vnew
          const float q1 = (n < NTAY) ? s1 : acc1;
          publish2(XW(buf, b), q0, q1, tg);
        }
        poll8(XW(buf, (ln << 2)), tg, wreg);
      }
      // vnew -> LDS; solo argmax; done flag
      *(float4*)(v_loc + l8)     = make_float4(wreg[0], wreg[1], wreg[2], wreg[3]);
      *(float4*)(v_loc + l8 + 4) = make_float4(wreg[4], wreg[5], wreg[6], wreg[7]);
      float mv = wreg[0]; int mi = l8;
#pragma unroll
      for (int k = 1; k < 8; ++k) if (wreg[k] > mv) { mv = wreg[k]; mi = l8 + k; }
#pragma unroll
      for (int off = 32; off > 0; off >>= 1) {
        float ov = __shfl_xor(mv, off, 64); int oi = __shfl_xor(mi, off, 64);
        if (ov > mv || (ov == mv && oi < mi)) { mv = ov; mi = oi; }
      }
      if (ln == 0) bc[0] = (mi == tgtIdx) ? 1 : 0;
    }
    __syncthreads();
    if (bc[0]) {
      d = 1;
    } else if (s + 1 < NSTEP) {
      // ---- local h1 for step s+1 (no exchange round). ----
      // Thread (jj, hh): partial dot over v[hh*256 .. +255].
      // Global tail (rows 192..255) issued FIRST -> loads pipeline under
      // the register-portion fma chain. All LDS v-reads are wave-uniform
      // (broadcast, conflict-free).
      const float4* vp4 = (const float4*)(v_loc + (hh << 8));
      const float* wgp = W1 + (((hh << 8) + 192) * 256) + jj;
      float acA = 0.f, acB = 0.f, acC = 0.f, acD = 0.f;
#define H1G4(k) { const float4 v4_ = vp4[48 + (k)]; \
      acA = fmaf(wgp[(4*(k))*256],     v4_.x, acA); \
      acB = fmaf(wgp[(4*(k)+1)*256],   v4_.y, acB); \
      acC = fmaf(wgp[(4*(k)+2)*256],   v4_.z, acC); \
      acD = fmaf(wgp[(4*(k)+3)*256],   v4_.w, acD); }
      REP16(H1G4, 0)
#undef H1G4
#define H1FMA(i) { const float4 v4_ = vp4[i]; \
      const float2 wa_ = __half22float2(w1h[2*(i)]); \
      const float2 wb_ = __half22float2(w1h[2*(i)+1]); \
      acA = fmaf(wa_.x, v4_.x, acA); acB = fmaf(wa_.y, v4_.y, acB); \
      acC = fmaf(wb_.x, v4_.z, acC); acD = fmaf(wb_.y, v4_.w, acD); }
      REP48(H1FMA, 0)
#undef H1FMA
      redp[tid] = (acA + acB) + (acC + acD);
      __syncthreads();
      if (tid < 256)
        h1_s[tid] = fmaxf(redp[tid] + redp[tid + 256] + cB_s[tid], 0.f);
      __syncthreads();
    }
    r += NTAY;
  }

  // ---- epilogue: all global writes (block 0 only) ----
  if (b == 0) {
    out[tid] = v_loc[tid];
    for (int i = tid; i < NSTEP * 64; i += NTHR)
      out[512 + i] = (i < nAct * 64) ? llog[i] : 0.0f;
  }
}

extern "C" void kernel_launch(void* const* d_in, const int* in_sizes, int n_in,
                              void* d_out, int out_size, void* d_ws, size_t ws_size,
                              hipStream_t stream) {
  (void)in_sizes; (void)n_in; (void)out_size; (void)ws_size;
  petri_kernel<<<dim3(NBLK), dim3(NTHR), 0, stream>>>(
      (const float*)d_in[0], (const float*)d_in[1], (const float*)d_in[2],
      (const float*)d_in[3], (const float*)d_in[4], (const float*)d_in[5],
      (const float*)d_in[6], (const float*)d_in[7], (const float*)d_in[8],
      (const float*)d_in[9], (ull*)d_ws, (float*)d_out);
}

// Round 7
// 320.638 us; speedup vs baseline: 3.9729x; 3.9694x over previous
//
#include <hip/hip_runtime.h>
#include <hip/hip_fp16.h>

// Persistent 256-block kernel (1 block/CU forced by ~155 KB LDS).
// Rows 2b,2b+1 of all 64 Omega_t cached ONCE in LDS as fp16 (validated
// R4-R8, absmax 0.0078). NTAY=3 Taylor terms of expm(A)@v.
//
// Exchange (fence-free): relaxed agent-scope 8-byte atomics only.
// TWO floats per word, tag in low-2 mantissa bits of float0 (one atom ->
// no ordering needed). 256 words per round, ONE PER 64B LINE (spread --
// R13 proved packing regresses: 8 publishers/line serialize at the
// coherence point). 4 rotating buffers (64 KB d_ws): buf0 = h1 rounds,
// buf1/2/3 = T1/T2/T3; tags cycle s&3 per buffer, period-16-round reuse.
// Skew induction (unchanged): block A overwrites buf0 word A (tail h1
// publish, end of step s) only after fully gathering T1,T2,T3 of step s;
// any block B published T1(s) only after fully gathering h1(s); so every
// block finished reading buf0 before the overwrite. Poison 0xAA low2=2
// != tag0 for the startup round; full-run leftovers all tag 3 != 0.
//
// FAILED experiments (counters, not vibes):
//  R12 (890us): device-wide atomicAdd h1-reduction serialized at MALL.
//  R13 (292us): packed exchange -> publisher line serialization.
//  R14/R15/R16 (1145-1202us): W1-top in registers spilled to scratch ALL
//    three ways (plain, macro-literal-idx, waves_per_eu(2,2)) -- allocator
//    pins 128 VGPR regardless; 1 GB/dispatch scratch traffic. ABANDONED.
//
// R17 (this round): revert to R11 core + the two R13 pieces that were
// NOT implicated in its regression:
//  - h1(s+1) published in the T3 tail (wave0: 8 fma + butterfly + cB,
//    ~60ns after the vnew gather, BEFORE argmax/barrier). The h1 round
//    becomes a poll-hit (~0.8us) instead of a full RT (~2.2us): the
//    store-visibility latency hides under argmax+barrier+loop overhead.
//  - ALL global stores deferred to epilogue via llog LDS (removes the
//    per-step vmcnt(0) store drain from block 0; blocks symmetric).
//  - ILP'd MLP chains (4-way L2, 2-way L3) from R13.

#define NBLK 256
#define NTHR 512
#define NSTEP 20
#define NTAY 3
#define RBUF 4

typedef unsigned long long ull;

// word i (i<256) of exchange buffer buf: 64 B apart (spread layout)
#define XW(buf, i) (X + ((((buf) << 8) + (i)) << 3))

__device__ __forceinline__ float wredsum(float p) {
#pragma unroll
  for (int off = 32; off > 0; off >>= 1) p += __shfl_xor(p, off, 64);
  return p;
}

__device__ __forceinline__ void wredsum2(float& p0, float& p1) {
#pragma unroll
  for (int off = 32; off > 0; off >>= 1) {
    float t0 = __shfl_xor(p0, off, 64);
    float t1 = __shfl_xor(p1, off, 64);
    p0 += t0;
    p1 += t1;
  }
}

__device__ __forceinline__ void publish2(ull* w, float v0, float v1, unsigned int tag2) {
  unsigned int u0 = (__float_as_uint(v0) & ~3u) | tag2;
  ull x = (ull)u0 | ((ull)__float_as_uint(v1) << 32);
  __hip_atomic_store(w, x, __ATOMIC_RELAXED, __HIP_MEMORY_SCOPE_AGENT);
}

__device__ __forceinline__ float2 poll2(ull* w, unsigned int tag2) {
  int it = 0;
  for (;;) {
    ull x = __hip_atomic_load(w, __ATOMIC_RELAXED, __HIP_MEMORY_SCOPE_AGENT);
    if ((unsigned int)(x & 3u) == tag2) {
      float2 r;
      r.x = __uint_as_float((unsigned int)x);
      r.y = __uint_as_float((unsigned int)(x >> 32));
      return r;
    }
    if (it == 0)      __builtin_amdgcn_s_sleep(1);
    else if (it == 1) __builtin_amdgcn_s_sleep(2);
    else              __builtin_amdgcn_s_sleep(4);
    if (it < 2) ++it;
  }
}

// lane-quad poll: 4 words (64 B apart) -> 8 floats; all 4 loads kept in
// flight per retry iteration (hand-unrolled, no runtime-indexed arrays).
__device__ __forceinline__ void poll8(ull* w0, unsigned int tg, float* o) {
  ull x0 = 0, x1 = 0, x2 = 0, x3 = 0;
  bool g0 = false, g1 = false, g2 = false, g3 = false;
  int it = 0;
  for (;;) {
    if (!g0) { ull x = __hip_atomic_load(w0,      __ATOMIC_RELAXED, __HIP_MEMORY_SCOPE_AGENT); if ((unsigned int)(x & 3u) == tg) { x0 = x; g0 = true; } }
    if (!g1) { ull x = __hip_atomic_load(w0 + 8,  __ATOMIC_RELAXED, __HIP_MEMORY_SCOPE_AGENT); if ((unsigned int)(x & 3u) == tg) { x1 = x; g1 = true; } }
    if (!g2) { ull x = __hip_atomic_load(w0 + 16, __ATOMIC_RELAXED, __HIP_MEMORY_SCOPE_AGENT); if ((unsigned int)(x & 3u) == tg) { x2 = x; g2 = true; } }
    if (!g3) { ull x = __hip_atomic_load(w0 + 24, __ATOMIC_RELAXED, __HIP_MEMORY_SCOPE_AGENT); if ((unsigned int)(x & 3u) == tg) { x3 = x; g3 = true; } }
    if (g0 && g1 && g2 && g3) break;
    if (it == 0)      __builtin_amdgcn_s_sleep(1);
    else if (it == 1) __builtin_amdgcn_s_sleep(2);
    else              __builtin_amdgcn_s_sleep(4);
    if (it < 2) ++it;
  }
  o[0] = __uint_as_float((unsigned int)x0); o[1] = __uint_as_float((unsigned int)(x0 >> 32));
  o[2] = __uint_as_float((unsigned int)x1); o[3] = __uint_as_float((unsigned int)(x1 >> 32));
  o[4] = __uint_as_float((unsigned int)x2); o[5] = __uint_as_float((unsigned int)(x2 >> 32));
  o[6] = __uint_as_float((unsigned int)x3); o[7] = __uint_as_float((unsigned int)(x3 >> 32));
}

__global__ __launch_bounds__(NTHR) void petri_kernel(
    const float* __restrict__ vsrc, const float* __restrict__ vtgt,
    const float* __restrict__ omg,  const float* __restrict__ W1,
    const float* __restrict__ b1,   const float* __restrict__ W2,
    const float* __restrict__ b2,   const float* __restrict__ W3,
    const float* __restrict__ b3,   const float* __restrict__ gum,
    ull* __restrict__ X, float* __restrict__ out) {
  __shared__ __half2 oh[64 * 512];   // 128 KB: {row2b[j], row2b+1[j]} per t
  __shared__ __align__(16) float A0_s[512];
  __shared__ __align__(16) float A1_s[512];
  __shared__ __align__(16) float v_loc[512];
  __shared__ float tgt_s[512];
  __shared__ float w1c_s[1024];      // W1 column b (both halves)
  __shared__ float gum_s[NSTEP * 64];
  __shared__ float b2_s[128], b3_s[64];
  __shared__ float soft_s[64], h1_s[256], h2_s[128];
  __shared__ float redp[512];
  __shared__ float llog[NSTEP * 64]; // deferred logits
  __shared__ float rf8[8];
  __shared__ int   ri8[8];
  __shared__ float cB_s[1];
  __shared__ int   bc[1];

  const int b = blockIdx.x, tid = threadIdx.x;
  const int wv = tid >> 6, ln = tid & 63;

  v_loc[tid] = vsrc[tid];
  tgt_s[tid] = vtgt[tid];
  w1c_s[tid] = W1[tid * 256 + b];
  w1c_s[tid + 512] = W1[(tid + 512) * 256 + b];
  for (int i = tid; i < NSTEP * 64; i += NTHR) gum_s[i] = gum[i];
  if (tid >= NTHR - 128) {
    int j = tid - (NTHR - 128);
    b2_s[j] = b2[j];
    if (j < 64) b3_s[j] = b3[j];
  }
  // W2 column slice in registers: thread (o=tid&127,q=tid>>7) holds
  // W2[(q*64+i)*128+o], i=0..63
  float w2r[64];
  {
    const int o = tid & 127, q = tid >> 7;
    const float* p = W2 + ((q << 6) * 128) + o;
#pragma unroll
    for (int i = 0; i < 64; ++i) w2r[i] = p[i * 128];
  }
  // W3 slice: thread (o=tid&63,q=tid>>6) holds W3[(q*16+i)*64+o], i=0..15
  float w3r[16];
  {
    const int o = tid & 63, q = tid >> 6;
    const float* p = W3 + ((q << 4) * 64) + o;
#pragma unroll
    for (int i = 0; i < 16; ++i) w3r[i] = p[i * 64];
  }
  // Omega rows 2b,2b+1 -> LDS fp16, float4-vectorized
  {
    const int tq = tid >> 7;            // 0..3 : t within group of 4
    const int c4 = (tid & 127) << 2;    // col 0..508 step 4
    const float* rp = omg + (b << 10) + c4;
#pragma unroll 4
    for (int g = 0; g < 16; ++g) {
      const int t = (g << 2) + tq;
      const float* p = rp + t * 262144;
      const float4 f0 = *(const float4*)(p);        // row 2b
      const float4 f1 = *(const float4*)(p + 512);  // row 2b+1
      __half2* dst = oh + t * 512 + c4;
      dst[0] = __floats2half2_rn(f0.x, f1.x);
      dst[1] = __floats2half2_rn(f0.y, f1.y);
      dst[2] = __floats2half2_rn(f0.z, f1.z);
      dst[3] = __floats2half2_rn(f0.w, f1.w);
    }
  }
  __syncthreads();

  // cB = b1[b] + dot(tgt, W1_bot[:,b])  -- off the per-step critical path
  {
    float p = tgt_s[tid] * w1c_s[tid + 512];
    p = wredsum(p);
    if (ln == 0) rf8[wv] = p;
    __syncthreads();
    if (tid == 0) {
      float a = b1[b];
      for (int q = 0; q < 8; ++q) a += rf8[q];
      cB_s[0] = a;
    }
    __syncthreads();
  }

  // target argmax (identical in every block), first-index tie-break
  int tgtIdx;
  {
    float v = tgt_s[tid]; int ix = tid;
#pragma unroll
    for (int off = 32; off > 0; off >>= 1) {
      float ov = __shfl_xor(v, off, 64); int oi = __shfl_xor(ix, off, 64);
      if (ov > v || (ov == v && oi < ix)) { v = ov; ix = oi; }
    }
    if (ln == 0) { rf8[wv] = v; ri8[wv] = ix; }
    __syncthreads();
    if (tid == 0) {
      float bv = rf8[0]; int bix = ri8[0];
      for (int q = 1; q < 8; ++q)
        if (rf8[q] > bv || (rf8[q] == bv && ri8[q] < bix)) { bv = rf8[q]; bix = ri8[q]; }
      bc[0] = bix;
    }
    __syncthreads();
    tgtIdx = bc[0];
    __syncthreads();
  }

  // wave0 register state: lane l owns vector elems 8l..8l+7 (= exchange
  // words 4l..4l+3) and the matching W1-top column slice.
  float vreg[8], w1t[8];
  if (wv == 0) {
    const int l8 = ln << 3;
#pragma unroll
    for (int k = 0; k < 8; ++k) { vreg[k] = v_loc[l8 + k]; w1t[k] = w1c_s[l8 + k]; }
    // startup: publish h1 of step 0 into round 0 (buf0, tag 0)
    float p = 0.f;
#pragma unroll
    for (int k = 0; k < 8; ++k) p = fmaf(vreg[k], w1t[k], p);
    p = wredsum(p);
    if (ln == 0) {
      float h = fmaxf(p + cB_s[0], 0.f);
      publish2(XW(0, b), h, h, 0u);
    }
  }

  int d = 0;
  int nAct = 0;  // number of active steps (uniform across blocks/threads)
  int r = 0;     // round counter: h1(s)=4s (buf0), T1/T2/T3 = 4s+1..3

  for (int s = 0; s < NSTEP; ++s) {
    if (d) continue;  // frozen (uniform across blocks); epilogue zero-fills
    nAct = s + 1;

    // ---- gather h1 (published at startup / in previous T3 tail) ----
    {
      const int buf = r & (RBUF - 1);
      const unsigned int tg = (unsigned int)((r >> 2) & 3);
      if (tid < 256) h1_s[tid] = poll2(XW(buf, tid), tg).x;
      __syncthreads();
      ++r;
    }

    // ---- replicated L2/L3/softmax from h1_s (register weights) ----
    {
      const int q = tid >> 7;
      const float* hp = h1_s + (q << 6);
      float a0 = 0.f, a1 = 0.f, a2 = 0.f, a3 = 0.f;
#pragma unroll
      for (int i = 0; i < 64; i += 4) {
        a0 = fmaf(hp[i],     w2r[i],     a0);
        a1 = fmaf(hp[i + 1], w2r[i + 1], a1);
        a2 = fmaf(hp[i + 2], w2r[i + 2], a2);
        a3 = fmaf(hp[i + 3], w2r[i + 3], a3);
      }
      redp[tid] = (a0 + a1) + (a2 + a3);
    }
    __syncthreads();
    if (tid < 128) {
      float rr = redp[tid] + redp[tid + 128] + redp[tid + 256] + redp[tid + 384] + b2_s[tid];
      h2_s[tid] = fmaxf(rr, 0.f);
    }
    __syncthreads();
    {
      const int q = tid >> 6;
      const float* hp = h2_s + (q << 4);
      float a0 = 0.f, a1 = 0.f;
#pragma unroll
      for (int i = 0; i < 16; i += 2) {
        a0 = fmaf(hp[i],     w3r[i],     a0);
        a1 = fmaf(hp[i + 1], w3r[i + 1], a1);
      }
      redp[tid] = a0 + a1;
    }
    __syncthreads();
    if (tid < 64) {
      float a = b3_s[tid];
#pragma unroll
      for (int q = 0; q < 8; ++q) a += redp[tid + (q << 6)];
      float lg = a + gum_s[s * 64 + tid];  // TAU = 1
      float mx = lg;
#pragma unroll
      for (int off = 32; off > 0; off >>= 1) mx = fmaxf(mx, __shfl_xor(mx, off, 64));
      float e = __expf(lg - mx);
      float sm = e;
#pragma unroll
      for (int off = 32; off > 0; off >>= 1) sm += __shfl_xor(sm, off, 64);
      soft_s[tid] = e / sm;
      llog[s * 64 + tid] = a;  // deferred logits
    }
    __syncthreads();

    // ---- mix 2 rows of A from LDS fp16 ----
    {
      float a0 = 0.f, a1 = 0.f, c0 = 0.f, c1 = 0.f;
#pragma unroll 8
      for (int t = 0; t < 64; t += 2) {
        float2 xy0 = __half22float2(oh[t * 512 + tid]);
        float2 xy1 = __half22float2(oh[(t + 1) * 512 + tid]);
        float s0 = soft_s[t], s1 = soft_s[t + 1];
        a0 = fmaf(s0, xy0.x, a0);
        c0 = fmaf(s0, xy0.y, c0);
        a1 = fmaf(s1, xy1.x, a1);
        c1 = fmaf(s1, xy1.y, c1);
      }
      A0_s[tid] = a0 + a1;
      A1_s[tid] = c0 + c1;
    }
    __syncthreads();

    // ---- rounds r..r+2: Taylor n=1..NTAY, wave0 solo, barrier-free.
    // T3 tail publishes h1(s+1) ~60ns after the vnew gather. ----
    if (wv == 0) {
      const int l8 = ln << 3;
      const float4 a00 = *(const float4*)(A0_s + l8);      // A row 2b
      const float4 a01 = *(const float4*)(A0_s + l8 + 4);
      const float4 a10 = *(const float4*)(A1_s + l8);      // A row 2b+1
      const float4 a11 = *(const float4*)(A1_s + l8 + 4);
      const float vb0 = v_loc[b << 1], vb1 = v_loc[(b << 1) + 1];
      float wreg[8];
#pragma unroll
      for (int k = 0; k < 8; ++k) wreg[k] = vreg[k];
      float acc0 = 0.f, acc1 = 0.f;
#pragma unroll
      for (int n = 1; n <= NTAY; ++n) {
        const int rr = r + (n - 1);
        const int buf = rr & (RBUF - 1);
        const unsigned int tg = (unsigned int)((rr >> 2) & 3);
        float p0 = 0.f, p1 = 0.f;
        p0 = fmaf(a00.x, wreg[0], p0); p0 = fmaf(a00.y, wreg[1], p0);
        p0 = fmaf(a00.z, wreg[2], p0); p0 = fmaf(a00.w, wreg[3], p0);
        p0 = fmaf(a01.x, wreg[4], p0); p0 = fmaf(a01.y, wreg[5], p0);
        p0 = fmaf(a01.z, wreg[6], p0); p0 = fmaf(a01.w, wreg[7], p0);
        p1 = fmaf(a10.x, wreg[0], p1); p1 = fmaf(a10.y, wreg[1], p1);
        p1 = fmaf(a10.z, wreg[2], p1); p1 = fmaf(a10.w, wreg[3], p1);
        p1 = fmaf(a11.x, wreg[4], p1); p1 = fmaf(a11.y, wreg[5], p1);
        p1 = fmaf(a11.z, wreg[6], p1); p1 = fmaf(a11.w, wreg[7], p1);
        wredsum2(p0, p1);
        if (ln == 0) {
          float s0, s1;
          if (n == 1) {
            s0 = p0; s1 = p1;
            acc0 = vb0 + s0; acc1 = vb1 + s1;
          } else {
            const float inv = (n == 2) ? 0.5f : (1.0f / 3.0f);
            s0 = p0 * inv; s1 = p1 * inv;
            acc0 += s0; acc1 += s1;
          }
          const float q0 = (n < NTAY) ? s0 : acc0;  // last round: vnew
          const float q1 = (n < NTAY) ? s1 : acc1;
          publish2(XW(buf, b), q0, q1, tg);
        }
        poll8(XW(buf, (ln << 2)), tg, wreg);
      }
      // h1(s+1) tail publish: round 4(s+1) (buf0, tag (s+1)&3). Safe by
      // induction: full gather of T1..T3(s) implies every block finished
      // reading buf0's h1(s).
      if (s + 1 < NSTEP) {
        const int rh = r + NTAY;
        const unsigned int tgh = (unsigned int)((rh >> 2) & 3);
        float ph = 0.f;
#pragma unroll
        for (int k = 0; k < 8; ++k) ph = fmaf(wreg[k], w1t[k], ph);
        ph = wredsum(ph);
        if (ln == 0) {
          float h = fmaxf(ph + cB_s[0], 0.f);
          publish2(XW(rh & (RBUF - 1), b), h, h, tgh);
        }
      }
      // vnew -> regs + LDS; solo argmax; done flag
#pragma unroll
      for (int k = 0; k < 8; ++k) vreg[k] = wreg[k];
      *(float4*)(v_loc + l8)     = make_float4(wreg[0], wreg[1], wreg[2], wreg[3]);
      *(float4*)(v_loc + l8 + 4) = make_float4(wreg[4], wreg[5], wreg[6], wreg[7]);
      float mv = wreg[0]; int mi = l8;
#pragma unroll
      for (int k = 1; k < 8; ++k) if (wreg[k] > mv) { mv = wreg[k]; mi = l8 + k; }
#pragma unroll
      for (int off = 32; off > 0; off >>= 1) {
        float ov = __shfl_xor(mv, off, 64); int oi = __shfl_xor(mi, off, 64);
        if (ov > mv || (ov == mv && oi < mi)) { mv = ov; mi = oi; }
      }
      if (ln == 0) bc[0] = (mi == tgtIdx) ? 1 : 0;
    }
    __syncthreads();
    if (bc[0]) d = 1;
    r += NTAY;
  }

  // ---- epilogue: all global writes (block 0 only) ----
  if (b == 0) {
    out[tid] = v_loc[tid];
    for (int i = tid; i < NSTEP * 64; i += NTHR)
      out[512 + i] = (i < nAct * 64) ? llog[i] : 0.0f;
  }
}

extern "C" void kernel_launch(void* const* d_in, const int* in_sizes, int n_in,
                              void* d_out, int out_size, void* d_ws, size_t ws_size,
                              hipStream_t stream) {
  (void)in_sizes; (void)n_in; (void)out_size; (void)ws_size;
  petri_kernel<<<dim3(NBLK), dim3(NTHR), 0, stream>>>(
      (const float*)d_in[0], (const float*)d_in[1], (const float*)d_in[2],
      (const float*)d_in[3], (const float*)d_in[4], (const float*)d_in[5],
      (const float*)d_in[6], (const float*)d_in[7], (const float*)d_in[8],
      (const float*)d_in[9], (ull*)d_ws, (float*)d_out);
}